// Round 8
// baseline (1023.917 us; speedup 1.0000x reference)
//
#include <hip/hip_runtime.h>
#include <hip/hip_bf16.h>

#define TT 96
#define BB 32
#define DIN 256
#define HH 512
#define VV 128
#define NB 256   // persistent blocks (1 per CU)

// raw barrier: orders LDS, leaves VMEM in flight (no vmcnt drain)
#define BAR() asm volatile("s_waitcnt lgkmcnt(0)\ns_barrier" ::: "memory")

// ---------------- Phase A: Z[t][g][h][b] = sum_d x[b][t][d] * Wg[t][h][d] ----------------
__global__ __launch_bounds__(256) void phaseA_kernel(
    const float* __restrict__ x,
    const float* __restrict__ Wf, const float* __restrict__ Wi,
    const float* __restrict__ Wc, const float* __restrict__ Wo,
    float* __restrict__ Z)
{
    int bid  = blockIdx.x;
    int t    = bid >> 4;
    int tile = bid & 15;
    int g    = tile >> 2;
    int h0   = (tile & 3) * 128;
    const float* W = (g == 0) ? Wf : (g == 1) ? Wi : (g == 2) ? Wc : Wo;

    __shared__ float4 Xs4[32 * 64];   // (b, q) at [b*64 + (q ^ (b&15))]
    __shared__ float4 Wc4[128 * 8];   // slot s=row*8+qs holds global quad qs ^ ((row>>2)&7)

    int tid = threadIdx.x;
    {
        int b   = tid >> 3;
        int kq8 = tid & 7;
        const float* src = x + ((size_t)b * TT + t) * DIN;
        int bx = b & 15;
        #pragma unroll
        for (int j = 0; j < 8; ++j) {
            int q = kq8 * 8 + j;
            Xs4[b * 64 + (q ^ bx)] = *reinterpret_cast<const float4*>(src + q * 4);
        }
    }

    int rg = tid >> 3;
    int bg = tid & 7;
    const float* wbase = W + ((size_t)t * HH + h0) * DIN;

    int srow[4], sgq[4];
    #pragma unroll
    for (int j = 0; j < 4; ++j) {
        int s = j * 256 + tid;
        srow[j] = s >> 3;
        sgq[j]  = (s & 7) ^ ((srow[j] >> 2) & 7);
    }

    float4 stg[4];
    #pragma unroll
    for (int j = 0; j < 4; ++j)
        stg[j] = *reinterpret_cast<const float4*>(wbase + (size_t)srow[j] * DIN + sgq[j] * 4);

    float acc[4][4];
    #pragma unroll
    for (int r = 0; r < 4; ++r)
        #pragma unroll
        for (int c = 0; c < 4; ++c) acc[r][c] = 0.f;

    for (int kc = 0; kc < 8; ++kc) {
        __syncthreads();
        #pragma unroll
        for (int j = 0; j < 4; ++j) Wc4[j * 256 + tid] = stg[j];
        __syncthreads();
        if (kc < 7) {
            #pragma unroll
            for (int j = 0; j < 4; ++j)
                stg[j] = *reinterpret_cast<const float4*>(
                    wbase + (size_t)srow[j] * DIN + (kc + 1) * 32 + sgq[j] * 4);
        }
        #pragma unroll
        for (int q = 0; q < 8; ++q) {
            float4 xv[4], wv[4];
            #pragma unroll
            for (int c = 0; c < 4; ++c) {
                int b = c * 8 + bg;
                xv[c] = Xs4[b * 64 + ((kc * 8 + q) ^ (b & 15))];
            }
            #pragma unroll
            for (int r = 0; r < 4; ++r)
                wv[r] = Wc4[(rg * 4 + r) * 8 + (q ^ (rg & 7))];
            #pragma unroll
            for (int r = 0; r < 4; ++r)
                #pragma unroll
                for (int c = 0; c < 4; ++c) {
                    acc[r][c] = fmaf(wv[r].x, xv[c].x, acc[r][c]);
                    acc[r][c] = fmaf(wv[r].y, xv[c].y, acc[r][c]);
                    acc[r][c] = fmaf(wv[r].z, xv[c].z, acc[r][c]);
                    acc[r][c] = fmaf(wv[r].w, xv[c].w, acc[r][c]);
                }
        }
    }

    size_t zbase = ((size_t)(t * 4 + g) * HH + h0 + rg * 4) * BB;
    #pragma unroll
    for (int r = 0; r < 4; ++r)
        #pragma unroll
        for (int c = 0; c < 4; ++c)
            Z[zbase + (size_t)r * BB + c * 8 + bg] = acc[r][c];
}

// ---------------- Phase B: persistent, raw barriers + flag-array global barrier ----------
// 256 blocks (2 h-rows each) x 512 threads. Step layout:
//   [A] waves4-7 issue W/Z/bias prefetch for t+1; all: GEMV over h(t-1)
//   BAR (lgkm only)  ->  [B] waves0-3: reduce+act   BAR
//   [C] wave0: c,h update, sc1 h-store, vmcnt(0), flag=t+1, poll 256 flags
//       waves4-7: consume prefetch (vmcnt waits overlap the poll)
//   BAR
__global__ __launch_bounds__(512, 2) void lstm_persistent(
    const float* __restrict__ Whf, const float* __restrict__ Whi,
    const float* __restrict__ Whc, const float* __restrict__ Who,
    const float* __restrict__ bf,  const float* __restrict__ bi,
    const float* __restrict__ bc,  const float* __restrict__ bo,
    const float* __restrict__ Z,   float* __restrict__ Hall,
    unsigned* __restrict__ flags)
{
    int blk = blockIdx.x;
    int r0  = blk * 2;
    int tid = threadIdx.x;
    int ks  = tid >> 4;          // 0..31, k-chunk of 16
    int bg  = tid & 15;          // b = 2bg, 2bg+1

    __shared__ float pre[32][8][32];   // [ks][rowloc*4+gate][b]
    __shared__ float act[8][32];

    float creg = 0.f;            // tid<64: c for (row r0+(tid>>5), b=tid&31)

    for (int t = 0; t < TT; ++t) {
        // ---- prefetch issue: waves 4-7 (tid>=256), next step's W/Z/bias ----
        float4 pfw[4];
        float4 pfz;
        float  pfb;
        bool pf_on = (t + 1 < TT) && (tid >= 256);
        int  idx   = tid - 256;              // 0..255
        if (pf_on) {
            #pragma unroll
            for (int j = 0; j < 4; ++j) {
                int f    = j * 256 + idx;    // 0..1023 float4s (16 KB of W rows)
                int gate = f >> 8;
                int rl   = (f >> 7) & 1;
                int q    = f & 127;
                const float* wsrc = ((gate == 0) ? Whf : (gate == 1) ? Whi :
                                     (gate == 2) ? Whc : Who)
                                    + ((size_t)(t + 1) * HH + r0 + rl) * HH + q * 4;
                pfw[j] = *reinterpret_cast<const float4*>(wsrc);
            }
            if (idx < 64) {
                int g2 = idx >> 4, rl = (idx >> 3) & 1, qq = idx & 7;
                pfz = *reinterpret_cast<const float4*>(
                    Z + ((size_t)((t + 1) * 4 + g2) * HH + r0 + rl) * BB + qq * 4);
            }
            if (idx < 8) {
                int g2 = idx >> 1, rl = idx & 1;
                const float* bp = (g2 == 0) ? bf : (g2 == 1) ? bi : (g2 == 2) ? bc : bo;
                pfb = bp[(size_t)(t + 1) * HH + r0 + rl];
            }
        }

        // ---- GEMV over h(t-1) ----
        float a[8][2];
        #pragma unroll
        for (int rg = 0; rg < 8; ++rg) { a[rg][0] = 0.f; a[rg][1] = 0.f; }

        if (t > 0) {
            int k0 = ks * 16;
            const float* hbase = Hall + (size_t)(t - 1) * HH * BB + (size_t)k0 * BB + 2 * bg;
            const float* wp[8];
            #pragma unroll
            for (int rl = 0; rl < 2; ++rl) {
                size_t wo = ((size_t)t * HH + r0 + rl) * HH + k0;
                wp[rl * 4 + 0] = Whf + wo;
                wp[rl * 4 + 1] = Whi + wo;
                wp[rl * 4 + 2] = Whc + wo;
                wp[rl * 4 + 3] = Who + wo;
            }
            #pragma unroll
            for (int q = 0; q < 4; ++q) {
                float2 hv[4];
                #pragma unroll
                for (int j = 0; j < 4; ++j)
                    hv[j] = *reinterpret_cast<const float2*>(hbase + (size_t)(q * 4 + j) * BB);
                #pragma unroll
                for (int rg = 0; rg < 8; ++rg) {
                    float4 w = *reinterpret_cast<const float4*>(wp[rg] + q * 4);
                    a[rg][0] = fmaf(w.x, hv[0].x, a[rg][0]); a[rg][1] = fmaf(w.x, hv[0].y, a[rg][1]);
                    a[rg][0] = fmaf(w.y, hv[1].x, a[rg][0]); a[rg][1] = fmaf(w.y, hv[1].y, a[rg][1]);
                    a[rg][0] = fmaf(w.z, hv[2].x, a[rg][0]); a[rg][1] = fmaf(w.z, hv[2].y, a[rg][1]);
                    a[rg][0] = fmaf(w.w, hv[3].x, a[rg][0]); a[rg][1] = fmaf(w.w, hv[3].y, a[rg][1]);
                }
            }
        }
        #pragma unroll
        for (int rg = 0; rg < 8; ++rg) {
            pre[ks][rg][2 * bg]     = a[rg][0];
            pre[ks][rg][2 * bg + 1] = a[rg][1];
        }

        BAR();   // pre[] visible; VMEM (prefetch) stays in flight

        if (tid < 256) {
            int rg2 = tid >> 5;          // rowloc*4+gate
            int b   = tid & 31;
            int row = r0 + (rg2 >> 2);
            int g   = rg2 & 3;
            float s = 0.f;
            #pragma unroll
            for (int k2 = 0; k2 < 32; ++k2) s += pre[k2][rg2][b];
            s += Z[((size_t)(t * 4 + g) * HH + row) * BB + b];
            if (t > 0) {
                const float* bp = (g == 0) ? bf : (g == 1) ? bi : (g == 2) ? bc : bo;
                s += bp[t * HH + row];
            }
            act[rg2][b] = (g == 2) ? tanhf(s) : 1.f / (1.f + __expf(-s));
        }

        BAR();   // act[] visible

        if (tid < 64) {
            int rl = tid >> 5, b = tid & 31;
            float cn = act[rl * 4 + 0][b] * creg + act[rl * 4 + 1][b] * act[rl * 4 + 2][b];
            creg = cn;
            float hn = act[rl * 4 + 3][b] * tanhf(cn);
            __hip_atomic_store(Hall + ((size_t)t * HH + r0 + rl) * BB + b, hn,
                               __ATOMIC_RELAXED, __HIP_MEMORY_SCOPE_AGENT);
            if (t + 1 < TT) {
                // drain only wave0's VMEM: its h stores (it issued no prefetch)
                asm volatile("s_waitcnt vmcnt(0)" ::: "memory");
                if (tid == 0)
                    __hip_atomic_store(&flags[blk], (unsigned)(t + 1),
                                       __ATOMIC_RELAXED, __HIP_MEMORY_SCOPE_AGENT);
                // poll all 256 flags: lane L checks flags[4L..4L+3] (2 u64 loads)
                {
                    const unsigned long long* f64 = (const unsigned long long*)flags;
                    unsigned long long tv = (unsigned long long)(unsigned)(t + 1);
                    tv |= tv << 32;
                    for (;;) {
                        unsigned long long v0 = __hip_atomic_load(
                            &f64[tid * 2], __ATOMIC_RELAXED, __HIP_MEMORY_SCOPE_AGENT);
                        unsigned long long v1 = __hip_atomic_load(
                            &f64[tid * 2 + 1], __ATOMIC_RELAXED, __HIP_MEMORY_SCOPE_AGENT);
                        if (__all(v0 == tv && v1 == tv)) break;
                        __builtin_amdgcn_s_sleep(1);
                    }
                }
            }
        } else if (pf_on) {
            // consume prefetch during wave0's poll window (vmcnt waits land here)
            float s = pfw[0].x + pfw[0].y + pfw[0].z + pfw[0].w
                    + pfw[1].x + pfw[1].y + pfw[1].z + pfw[1].w
                    + pfw[2].x + pfw[2].y + pfw[2].z + pfw[2].w
                    + pfw[3].x + pfw[3].y + pfw[3].z + pfw[3].w;
            if (idx < 64) s += pfz.x + pfz.y + pfz.z + pfz.w;
            if (idx < 8)  s += pfb;
            asm volatile("" :: "v"(s));
        }

        BAR();   // all waves released once wave0's poll completes
    }
}

// ---------------- Phase C ----------------
__global__ __launch_bounds__(256) void phaseC_kernel(
    const float* __restrict__ lw, const float* __restrict__ lb,
    const float* __restrict__ Hall, float* __restrict__ out)
{
    int t  = blockIdx.x >> 2;
    int v0 = (blockIdx.x & 3) << 5;
    int tid = threadIdx.x;
    int v  = v0 + (tid >> 3);
    int bg = tid & 7;
    const float* w  = lw + ((size_t)t * VV + v) * HH;
    const float* hp = Hall + (size_t)t * HH * BB;
    float acc0 = 0.f, acc1 = 0.f, acc2 = 0.f, acc3 = 0.f;
    #pragma unroll 4
    for (int k = 0; k < HH; ++k) {
        float wv = w[k];
        float4 hv = *reinterpret_cast<const float4*>(hp + (size_t)k * BB + bg * 4);
        acc0 = fmaf(wv, hv.x, acc0);
        acc1 = fmaf(wv, hv.y, acc1);
        acc2 = fmaf(wv, hv.z, acc2);
        acc3 = fmaf(wv, hv.w, acc3);
    }
    float bias = lb[t * VV + v];
    float r[4] = {acc0 + bias, acc1 + bias, acc2 + bias, acc3 + bias};
    #pragma unroll
    for (int j = 0; j < 4; ++j) {
        int b = bg * 4 + j;
        out[((size_t)b * TT + t) * VV + v] = r[j];
    }
}

extern "C" void kernel_launch(void* const* d_in, const int* in_sizes, int n_in,
                              void* d_out, int out_size, void* d_ws, size_t ws_size,
                              hipStream_t stream)
{
    const float* x     = (const float*)d_in[0];
    const float* Wif   = (const float*)d_in[1];
    const float* Wii   = (const float*)d_in[2];
    const float* Wic   = (const float*)d_in[3];
    const float* Wio   = (const float*)d_in[4];
    const float* Whf_w = (const float*)d_in[5];
    const float* Whf_b = (const float*)d_in[6];
    const float* Whi_w = (const float*)d_in[7];
    const float* Whi_b = (const float*)d_in[8];
    const float* Whc_w = (const float*)d_in[9];
    const float* Whc_b = (const float*)d_in[10];
    const float* Who_w = (const float*)d_in[11];
    const float* Who_b = (const float*)d_in[12];
    const float* lin_w = (const float*)d_in[13];
    const float* lin_b = (const float*)d_in[14];
    float* out = (float*)d_out;

    float*    Z     = (float*)d_ws;                            // 96*4*512*32 floats
    float*    Hall  = Z + (size_t)TT * 4 * HH * BB;            // 96*512*32 floats
    unsigned* flags = (unsigned*)(Hall + (size_t)TT * HH * BB);  // 256 uints

    hipMemsetAsync(flags, 0, NB * sizeof(unsigned), stream);

    phaseA_kernel<<<dim3(TT * 16), dim3(256), 0, stream>>>(x, Wif, Wii, Wic, Wio, Z);

    lstm_persistent<<<dim3(NB), dim3(512), 0, stream>>>(
        Whf_w, Whi_w, Whc_w, Who_w, Whf_b, Whi_b, Whc_b, Who_b, Z, Hall, flags);

    phaseC_kernel<<<dim3(TT * 4), dim3(256), 0, stream>>>(lin_w, lin_b, Hall, out);
}

// Round 9
// 974.191 us; speedup vs baseline: 1.0510x; 1.0510x over previous
//
#include <hip/hip_runtime.h>
#include <hip/hip_bf16.h>

#define TT 96
#define BB 32
#define DIN 256
#define HH 512
#define VV 128
#define NB 256   // persistent blocks (1 per CU)

// raw barrier: orders LDS, leaves VMEM in flight (no vmcnt drain)
#define BAR() asm volatile("s_waitcnt lgkmcnt(0)\ns_barrier" ::: "memory")

// ---------------- Phase A: Z[t][g][h][b] = sum_d x[b][t][d] * Wg[t][h][d] ----------------
__global__ __launch_bounds__(256) void phaseA_kernel(
    const float* __restrict__ x,
    const float* __restrict__ Wf, const float* __restrict__ Wi,
    const float* __restrict__ Wc, const float* __restrict__ Wo,
    float* __restrict__ Z)
{
    int bid  = blockIdx.x;
    int t    = bid >> 4;
    int tile = bid & 15;
    int g    = tile >> 2;
    int h0   = (tile & 3) * 128;
    const float* W = (g == 0) ? Wf : (g == 1) ? Wi : (g == 2) ? Wc : Wo;

    __shared__ float4 Xs4[32 * 64];   // (b, q) at [b*64 + (q ^ (b&15))]
    __shared__ float4 Wc4[128 * 8];   // slot s=row*8+qs holds global quad qs ^ ((row>>2)&7)

    int tid = threadIdx.x;
    {
        int b   = tid >> 3;
        int kq8 = tid & 7;
        const float* src = x + ((size_t)b * TT + t) * DIN;
        int bx = b & 15;
        #pragma unroll
        for (int j = 0; j < 8; ++j) {
            int q = kq8 * 8 + j;
            Xs4[b * 64 + (q ^ bx)] = *reinterpret_cast<const float4*>(src + q * 4);
        }
    }

    int rg = tid >> 3;
    int bg = tid & 7;
    const float* wbase = W + ((size_t)t * HH + h0) * DIN;

    int srow[4], sgq[4];
    #pragma unroll
    for (int j = 0; j < 4; ++j) {
        int s = j * 256 + tid;
        srow[j] = s >> 3;
        sgq[j]  = (s & 7) ^ ((srow[j] >> 2) & 7);
    }

    float4 stg[4];
    #pragma unroll
    for (int j = 0; j < 4; ++j)
        stg[j] = *reinterpret_cast<const float4*>(wbase + (size_t)srow[j] * DIN + sgq[j] * 4);

    float acc[4][4];
    #pragma unroll
    for (int r = 0; r < 4; ++r)
        #pragma unroll
        for (int c = 0; c < 4; ++c) acc[r][c] = 0.f;

    for (int kc = 0; kc < 8; ++kc) {
        __syncthreads();
        #pragma unroll
        for (int j = 0; j < 4; ++j) Wc4[j * 256 + tid] = stg[j];
        __syncthreads();
        if (kc < 7) {
            #pragma unroll
            for (int j = 0; j < 4; ++j)
                stg[j] = *reinterpret_cast<const float4*>(
                    wbase + (size_t)srow[j] * DIN + (kc + 1) * 32 + sgq[j] * 4);
        }
        #pragma unroll
        for (int q = 0; q < 8; ++q) {
            float4 xv[4], wv[4];
            #pragma unroll
            for (int c = 0; c < 4; ++c) {
                int b = c * 8 + bg;
                xv[c] = Xs4[b * 64 + ((kc * 8 + q) ^ (b & 15))];
            }
            #pragma unroll
            for (int r = 0; r < 4; ++r)
                wv[r] = Wc4[(rg * 4 + r) * 8 + (q ^ (rg & 7))];
            #pragma unroll
            for (int r = 0; r < 4; ++r)
                #pragma unroll
                for (int c = 0; c < 4; ++c) {
                    acc[r][c] = fmaf(wv[r].x, xv[c].x, acc[r][c]);
                    acc[r][c] = fmaf(wv[r].y, xv[c].y, acc[r][c]);
                    acc[r][c] = fmaf(wv[r].z, xv[c].z, acc[r][c]);
                    acc[r][c] = fmaf(wv[r].w, xv[c].w, acc[r][c]);
                }
        }
    }

    size_t zbase = ((size_t)(t * 4 + g) * HH + h0 + rg * 4) * BB;
    #pragma unroll
    for (int r = 0; r < 4; ++r)
        #pragma unroll
        for (int c = 0; c < 4; ++c)
            Z[zbase + (size_t)r * BB + c * 8 + bg] = acc[r][c];
}

// ---------------- Phase B: persistent dataflow pipeline (no global barrier) --------------
// 256 blocks (2 h-rows each) x 512 threads (32 k-chunks of 16 x 16 b-pairs).
// Per step: each wave w polls only its 32 producer flags (blocks 32w..32w+31,
// supplying k in [64w,64w+64)), GEMVs its slice into pre[t&1], ONE intra-block
// barrier, then wave 0 alone does reduce+activations+c/h+publish (its 64 lanes
// = 2 rows x 32 batch; c in registers) while waves 1-7 run ahead into step t+1.
__global__ __launch_bounds__(512, 2) void lstm_persistent(
    const float* __restrict__ Whf, const float* __restrict__ Whi,
    const float* __restrict__ Whc, const float* __restrict__ Who,
    const float* __restrict__ bf,  const float* __restrict__ bi,
    const float* __restrict__ bc,  const float* __restrict__ bo,
    const float* __restrict__ Z,   float* __restrict__ Hall,
    unsigned* __restrict__ flags)
{
    int blk  = blockIdx.x;
    int r0   = blk * 2;
    int tid  = threadIdx.x;
    int ks   = tid >> 4;          // 0..31, k-chunk of 16
    int bg   = tid & 15;          // b = 2bg, 2bg+1
    int wid  = tid >> 6;          // wave 0..7
    int lane = tid & 63;

    __shared__ float pre[2][32][8][32];   // 64 KB, parity double-buffered

    float creg = 0.f;             // wave0 lane (rl,b): c for (row r0+(lane>>5), b=lane&31)

    for (int t = 0; t < TT; ++t) {
        int p = t & 1;

        // ---- prefetch issue: waves 4-7, next step's W rows + Z rows ----
        float4 pfw[4];
        float4 pfz;
        bool pf_on = (t + 1 < TT) && (wid >= 4);
        int  idx   = tid - 256;              // 0..255 when pf_on
        if (pf_on) {
            #pragma unroll
            for (int j = 0; j < 4; ++j) {
                int f    = j * 256 + idx;    // 0..1023 float4s (16 KB of W rows)
                int gate = f >> 8;
                int rl   = (f >> 7) & 1;
                int q    = f & 127;
                const float* wsrc = ((gate == 0) ? Whf : (gate == 1) ? Whi :
                                     (gate == 2) ? Whc : Who)
                                    + ((size_t)(t + 1) * HH + r0 + rl) * HH + q * 4;
                pfw[j] = *reinterpret_cast<const float4*>(wsrc);
            }
            if (idx < 64) {
                int g2 = idx >> 4, rl = (idx >> 3) & 1, qq = idx & 7;
                pfz = *reinterpret_cast<const float4*>(
                    Z + ((size_t)((t + 1) * 4 + g2) * HH + r0 + rl) * BB + qq * 4);
            }
        }

        if (t > 0) {
            // ---- per-wave producer-window poll: flags[32w .. 32w+31] >= t ----
            {
                const unsigned* myf = flags + wid * 32 + (lane & 31);
                for (;;) {
                    unsigned v = __hip_atomic_load(myf, __ATOMIC_RELAXED,
                                                   __HIP_MEMORY_SCOPE_AGENT);
                    if (__all((int)(v >= (unsigned)t))) break;
                    __builtin_amdgcn_s_sleep(1);
                }
            }

            // ---- GEMV slice over h(t-1), k in [ks*16, ks*16+16) ----
            float a[8][2];
            #pragma unroll
            for (int rg = 0; rg < 8; ++rg) { a[rg][0] = 0.f; a[rg][1] = 0.f; }

            int k0 = ks * 16;
            const float* hbase = Hall + (size_t)(t - 1) * HH * BB + (size_t)k0 * BB + 2 * bg;
            const float* wp[8];
            #pragma unroll
            for (int rl = 0; rl < 2; ++rl) {
                size_t wo = ((size_t)t * HH + r0 + rl) * HH + k0;
                wp[rl * 4 + 0] = Whf + wo;
                wp[rl * 4 + 1] = Whi + wo;
                wp[rl * 4 + 2] = Whc + wo;
                wp[rl * 4 + 3] = Who + wo;
            }
            #pragma unroll
            for (int q = 0; q < 4; ++q) {
                float2 hv[4];
                #pragma unroll
                for (int j = 0; j < 4; ++j)
                    hv[j] = *reinterpret_cast<const float2*>(hbase + (size_t)(q * 4 + j) * BB);
                #pragma unroll
                for (int rg = 0; rg < 8; ++rg) {
                    float4 w = *reinterpret_cast<const float4*>(wp[rg] + q * 4);
                    a[rg][0] = fmaf(w.x, hv[0].x, a[rg][0]); a[rg][1] = fmaf(w.x, hv[0].y, a[rg][1]);
                    a[rg][0] = fmaf(w.y, hv[1].x, a[rg][0]); a[rg][1] = fmaf(w.y, hv[1].y, a[rg][1]);
                    a[rg][0] = fmaf(w.z, hv[2].x, a[rg][0]); a[rg][1] = fmaf(w.z, hv[2].y, a[rg][1]);
                    a[rg][0] = fmaf(w.w, hv[3].x, a[rg][0]); a[rg][1] = fmaf(w.w, hv[3].y, a[rg][1]);
                }
            }
            #pragma unroll
            for (int rg = 0; rg < 8; ++rg) {
                pre[p][ks][rg][2 * bg]     = a[rg][0];
                pre[p][ks][rg][2 * bg + 1] = a[rg][1];
            }
        }

        // consume prefetch (vmcnt waits land here; issued ~1 GEMV earlier)
        if (pf_on) {
            float s = pfw[0].x + pfw[0].y + pfw[0].z + pfw[0].w
                    + pfw[1].x + pfw[1].y + pfw[1].z + pfw[1].w
                    + pfw[2].x + pfw[2].y + pfw[2].z + pfw[2].w
                    + pfw[3].x + pfw[3].y + pfw[3].z + pfw[3].w;
            if (idx < 64) s += pfz.x + pfz.y + pfz.z + pfz.w;
            asm volatile("" :: "v"(s));
        }

        BAR();   // pre[p] complete; the ONLY block-wide join per step

        // ---- wave 0: reduce + activations + c/h update + publish ----
        if (wid == 0) {
            int rl  = lane >> 5;
            int b   = lane & 31;
            int row = r0 + rl;
            float s0 = 0.f, s1 = 0.f, s2 = 0.f, s3 = 0.f;
            if (t > 0) {
                #pragma unroll
                for (int k2 = 0; k2 < 32; ++k2) {
                    s0 += pre[p][k2][rl * 4 + 0][b];
                    s1 += pre[p][k2][rl * 4 + 1][b];
                    s2 += pre[p][k2][rl * 4 + 2][b];
                    s3 += pre[p][k2][rl * 4 + 3][b];
                }
                s0 += bf[t * HH + row];
                s1 += bi[t * HH + row];
                s2 += bc[t * HH + row];
                s3 += bo[t * HH + row];
            }
            s0 += Z[((size_t)(t * 4 + 0) * HH + row) * BB + b];
            s1 += Z[((size_t)(t * 4 + 1) * HH + row) * BB + b];
            s2 += Z[((size_t)(t * 4 + 2) * HH + row) * BB + b];
            s3 += Z[((size_t)(t * 4 + 3) * HH + row) * BB + b];

            float f  = 1.f / (1.f + __expf(-s0));
            float i  = 1.f / (1.f + __expf(-s1));
            float cb = tanhf(s2);
            float o  = 1.f / (1.f + __expf(-s3));
            float cn = f * creg + i * cb;
            creg = cn;
            float hn = o * tanhf(cn);

            __hip_atomic_store(Hall + ((size_t)t * HH + row) * BB + b, hn,
                               __ATOMIC_RELAXED, __HIP_MEMORY_SCOPE_AGENT);
            asm volatile("s_waitcnt vmcnt(0)" ::: "memory");   // h visible at IC
            if (lane == 0)
                __hip_atomic_store(&flags[blk], (unsigned)(t + 1),
                                   __ATOMIC_RELAXED, __HIP_MEMORY_SCOPE_AGENT);
        }
        // waves 1-7 flow directly into step t+1 (poll their windows); wave 0
        // rejoins them at the next BAR.
    }
}

// ---------------- Phase C ----------------
__global__ __launch_bounds__(256) void phaseC_kernel(
    const float* __restrict__ lw, const float* __restrict__ lb,
    const float* __restrict__ Hall, float* __restrict__ out)
{
    int t  = blockIdx.x >> 2;
    int v0 = (blockIdx.x & 3) << 5;
    int tid = threadIdx.x;
    int v  = v0 + (tid >> 3);
    int bg = tid & 7;
    const float* w  = lw + ((size_t)t * VV + v) * HH;
    const float* hp = Hall + (size_t)t * HH * BB;
    float acc0 = 0.f, acc1 = 0.f, acc2 = 0.f, acc3 = 0.f;
    #pragma unroll 4
    for (int k = 0; k < HH; ++k) {
        float wv = w[k];
        float4 hv = *reinterpret_cast<const float4*>(hp + (size_t)k * BB + bg * 4);
        acc0 = fmaf(wv, hv.x, acc0);
        acc1 = fmaf(wv, hv.y, acc1);
        acc2 = fmaf(wv, hv.z, acc2);
        acc3 = fmaf(wv, hv.w, acc3);
    }
    float bias = lb[t * VV + v];
    float r[4] = {acc0 + bias, acc1 + bias, acc2 + bias, acc3 + bias};
    #pragma unroll
    for (int j = 0; j < 4; ++j) {
        int b = bg * 4 + j;
        out[((size_t)b * TT + t) * VV + v] = r[j];
    }
}

extern "C" void kernel_launch(void* const* d_in, const int* in_sizes, int n_in,
                              void* d_out, int out_size, void* d_ws, size_t ws_size,
                              hipStream_t stream)
{
    const float* x     = (const float*)d_in[0];
    const float* Wif   = (const float*)d_in[1];
    const float* Wii   = (const float*)d_in[2];
    const float* Wic   = (const float*)d_in[3];
    const float* Wio   = (const float*)d_in[4];
    const float* Whf_w = (const float*)d_in[5];
    const float* Whf_b = (const float*)d_in[6];
    const float* Whi_w = (const float*)d_in[7];
    const float* Whi_b = (const float*)d_in[8];
    const float* Whc_w = (const float*)d_in[9];
    const float* Whc_b = (const float*)d_in[10];
    const float* Who_w = (const float*)d_in[11];
    const float* Who_b = (const float*)d_in[12];
    const float* lin_w = (const float*)d_in[13];
    const float* lin_b = (const float*)d_in[14];
    float* out = (float*)d_out;

    float*    Z     = (float*)d_ws;                            // 96*4*512*32 floats
    float*    Hall  = Z + (size_t)TT * 4 * HH * BB;            // 96*512*32 floats
    unsigned* flags = (unsigned*)(Hall + (size_t)TT * HH * BB);  // 256 uints

    hipMemsetAsync(flags, 0, NB * sizeof(unsigned), stream);

    phaseA_kernel<<<dim3(TT * 16), dim3(256), 0, stream>>>(x, Wif, Wii, Wic, Wio, Z);

    lstm_persistent<<<dim3(NB), dim3(512), 0, stream>>>(
        Whf_w, Whi_w, Whc_w, Who_w, Whf_b, Whi_b, Whc_b, Who_b, Z, Hall, flags);

    phaseC_kernel<<<dim3(TT * 4), dim3(256), 0, stream>>>(lin_w, lin_b, Hall, out);
}